// Round 7
// baseline (514.456 us; speedup 1.0000x reference)
//
#include <hip/hip_runtime.h>
#include <hip/hip_cooperative_groups.h>

#define N_NODES 50000
#define N_EDGES 800000
#define IN_DIM 256
#define HID 64
#define OUT_DIM 16
#define GAT_IN 66   // HID + N_PROTO
#define NB_CSR 196  // 196*256 = 50176 >= N_NODES

typedef unsigned short u16;
typedef unsigned int u32;
typedef __attribute__((ext_vector_type(8))) short s8v;   // 8 bf16 (4 VGPRs)
typedef __attribute__((ext_vector_type(4))) float f4v;   // MFMA accumulator

__device__ __forceinline__ float bf2f(u16 u) {
  union { u32 i; float f; } v; v.i = ((u32)u) << 16; return v.f;
}
__device__ __forceinline__ u16 f2bf(float f) {
  union { float f; u32 i; } v; v.f = f;
  u32 r = v.i + 0x7FFFu + ((v.i >> 16) & 1u);
  return (u16)(r >> 16);
}
__device__ __forceinline__ void split8(const float* uu, s8v& ah, s8v& al) {
  #pragma unroll
  for (int j = 0; j < 8; ++j) {
    u32 bits = __float_as_uint(uu[j]);
    u16 hb = (u16)(bits >> 16);
    ah[j] = (short)hb;
    al[j] = (short)f2bf(uu[j] - bf2f(hb));
  }
}

// ---------------------------------------------------------------------------
// K_CSR (cooperative, 196 blocks x 256): zero deg + dtype detect -> hist ->
// block reduce -> block-sums scan -> block-local scan -> scatter.
// Replaces 6 separate launches.
// ---------------------------------------------------------------------------
__global__ __launch_bounds__(256) void k_csr(
    const void* __restrict__ ei, int* __restrict__ flag_i,
    int* __restrict__ deg, int* __restrict__ bsum, int* __restrict__ boff,
    int* __restrict__ off, int* __restrict__ cur, int* __restrict__ esrc)
{
  cooperative_groups::grid_group grid = cooperative_groups::this_grid();
  const int t = threadIdx.x, b = blockIdx.x;
  const int gtid = b * 256 + t;
  const int lane = t & 63;
  __shared__ int wtmp[4];

  // P0: zero deg; thread 0 detects int64 vs int32
  for (int i = gtid; i < N_NODES; i += NB_CSR * 256) deg[i] = 0;
  if (gtid == 0) {
    const long long* e64 = (const long long*)ei;
    int ok = 1;
    for (int k = 0; k < 64; k++) {
      long long v = e64[k];
      if (v < 0 || v >= N_NODES) { ok = 0; break; }
    }
    *flag_i = ok;
  }
  grid.sync();

  // P1: histogram of dst
  const int isl = *flag_i;
  if (isl) {
    const long long* e = (const long long*)ei + N_EDGES;
    for (int i = gtid; i < N_EDGES; i += NB_CSR * 256) {
      int d = (int)e[i];
      if ((unsigned)d < N_NODES) atomicAdd(&deg[d], 1);
    }
  } else {
    const int* e = (const int*)ei + N_EDGES;
    for (int i = gtid; i < N_EDGES; i += NB_CSR * 256) {
      int d = e[i];
      if ((unsigned)d < N_NODES) atomicAdd(&deg[d], 1);
    }
  }
  grid.sync();

  // P2: per-block sum of its 256-chunk
  const int idx = b * 256 + t;
  const int v = (idx < N_NODES) ? deg[idx] : 0;
  {
    int r = v;
    #pragma unroll
    for (int d = 1; d < 64; d <<= 1) r += __shfl_xor(r, d);
    if (lane == 0) wtmp[t >> 6] = r;
  }
  __syncthreads();
  if (t == 0) bsum[b] = wtmp[0] + wtmp[1] + wtmp[2] + wtmp[3];
  grid.sync();

  // P3: block 0 exclusive-scans the 196 block sums
  if (b == 0) {
    int sv = (t < NB_CSR) ? bsum[t] : 0;
    int inc = sv;
    #pragma unroll
    for (int d = 1; d < 64; d <<= 1) {
      int u = __shfl_up(inc, d);
      if (lane >= d) inc += u;
    }
    __shared__ int wt2[4];
    if (lane == 63) wt2[t >> 6] = inc;
    __syncthreads();
    int add = 0;
    for (int w = 0; w < (t >> 6); ++w) add += wt2[w];
    if (t < NB_CSR) boff[t] = add + inc - sv;
  }
  grid.sync();

  // P4: block-local exclusive scan + boff -> off, cur
  {
    int inc = v;
    #pragma unroll
    for (int d = 1; d < 64; d <<= 1) {
      int u = __shfl_up(inc, d);
      if (lane >= d) inc += u;
    }
    __syncthreads();  // wtmp reuse
    if (lane == 63) wtmp[t >> 6] = inc;
    __syncthreads();
    int add = boff[b];
    for (int w = 0; w < (t >> 6); ++w) add += wtmp[w];
    int ex = add + inc - v;
    if (idx < N_NODES) { off[idx] = ex; cur[idx] = ex; }
    if (idx == N_NODES - 1) off[N_NODES] = ex + v;
  }
  grid.sync();

  // P5: scatter src into CSR slots
  if (isl) {
    const long long* es = (const long long*)ei;
    const long long* ed = es + N_EDGES;
    for (int i = gtid; i < N_EDGES; i += NB_CSR * 256) {
      int d = (int)ed[i];
      if ((unsigned)d >= N_NODES) continue;
      int s = (int)es[i];
      if ((unsigned)s >= N_NODES) s = 0;
      int p = atomicAdd(&cur[d], 1);
      if ((unsigned)p < N_EDGES) esrc[p] = s;
    }
  } else {
    const int* es = (const int*)ei;
    const int* ed = es + N_EDGES;
    for (int i = gtid; i < N_EDGES; i += NB_CSR * 256) {
      int d = ed[i];
      if ((unsigned)d >= N_NODES) continue;
      int s = es[i];
      if ((unsigned)s >= N_NODES) s = 0;
      int p = atomicAdd(&cur[d], 1);
      if ((unsigned)p < N_EDGES) esrc[p] = s;
    }
  }
}

// ---------------------------------------------------------------------------
// K1 (MFMA): h = relu(x @ W_in + b_in); sem = cosine sim vs prototypes.
// ---------------------------------------------------------------------------
__global__ __launch_bounds__(256) void k_haug(
    const float* __restrict__ x, const float* __restrict__ Win,
    const float* __restrict__ bin, const float* __restrict__ proto,
    float* __restrict__ ha)
{
  __shared__ u16 wb[8 * 4 * 64 * 8];  // 32 KB: [s][t][l][j] = Win[k][c]
  for (int m = threadIdx.x; m < 16384; m += 256) {
    int j = m & 7, l = (m >> 3) & 63, t = (m >> 9) & 3, s = m >> 11;
    int k = s * 32 + (l >> 4) * 8 + j;
    int c = t * 16 + (l & 15);
    wb[m] = f2bf(Win[k * 64 + c]);
  }
  __syncthreads();
  const int lane = threadIdx.x & 63;
  const int nb = blockIdx.x * 64 + (threadIdx.x >> 6) * 16;
  if (nb >= N_NODES) return;
  const int mrow = lane & 15, q = lane >> 4;

  f4v acc0 = {0.f,0.f,0.f,0.f}, acc1 = {0.f,0.f,0.f,0.f};
  f4v acc2 = {0.f,0.f,0.f,0.f}, acc3 = {0.f,0.f,0.f,0.f};
  const float* xrow = x + (size_t)(nb + mrow) * IN_DIM + q * 8;
  #pragma unroll 2
  for (int s = 0; s < 8; ++s) {
    float4 u0 = *(const float4*)(xrow + s * 32);
    float4 u1 = *(const float4*)(xrow + s * 32 + 4);
    float uu[8] = {u0.x, u0.y, u0.z, u0.w, u1.x, u1.y, u1.z, u1.w};
    s8v ah, al;
    split8(uu, ah, al);
    const u16* wp = &wb[s * 2048 + lane * 8];
    s8v b0 = *(const s8v*)(wp);
    s8v b1 = *(const s8v*)(wp + 512);
    s8v b2 = *(const s8v*)(wp + 1024);
    s8v b3 = *(const s8v*)(wp + 1536);
    acc0 = __builtin_amdgcn_mfma_f32_16x16x32_bf16(ah, b0, acc0, 0, 0, 0);
    acc0 = __builtin_amdgcn_mfma_f32_16x16x32_bf16(al, b0, acc0, 0, 0, 0);
    acc1 = __builtin_amdgcn_mfma_f32_16x16x32_bf16(ah, b1, acc1, 0, 0, 0);
    acc1 = __builtin_amdgcn_mfma_f32_16x16x32_bf16(al, b1, acc1, 0, 0, 0);
    acc2 = __builtin_amdgcn_mfma_f32_16x16x32_bf16(ah, b2, acc2, 0, 0, 0);
    acc2 = __builtin_amdgcn_mfma_f32_16x16x32_bf16(al, b2, acc2, 0, 0, 0);
    acc3 = __builtin_amdgcn_mfma_f32_16x16x32_bf16(ah, b3, acc3, 0, 0, 0);
    acc3 = __builtin_amdgcn_mfma_f32_16x16x32_bf16(al, b3, acc3, 0, 0, 0);
  }

  float bt[4], p0t[4], p1t[4];
  #pragma unroll
  for (int t = 0; t < 4; ++t) {
    bt[t]  = bin[t * 16 + mrow];
    p0t[t] = proto[t * 16 + mrow];
    p1t[t] = proto[64 + t * 16 + mrow];
  }
  float np0 = 0.f, np1 = 0.f;
  #pragma unroll
  for (int t = 0; t < 4; ++t) { np0 += p0t[t] * p0t[t]; np1 += p1t[t] * p1t[t]; }
  #pragma unroll
  for (int mm = 1; mm < 16; mm <<= 1) {
    np0 += __shfl_xor(np0, mm); np1 += __shfl_xor(np1, mm);
  }
  const float ip0 = 1.f / (sqrtf(np0) + 1e-12f);
  const float ip1 = 1.f / (sqrtf(np1) + 1e-12f);

  float hcol[4][4];
  #pragma unroll
  for (int r = 0; r < 4; ++r) {
    hcol[0][r] = fmaxf(acc0[r] + bt[0], 0.f);
    hcol[1][r] = fmaxf(acc1[r] + bt[1], 0.f);
    hcol[2][r] = fmaxf(acc2[r] + bt[2], 0.f);
    hcol[3][r] = fmaxf(acc3[r] + bt[3], 0.f);
  }
  #pragma unroll
  for (int r = 0; r < 4; ++r) {
    float r0 = 0.f, r1 = 0.f, r2 = 0.f;
    #pragma unroll
    for (int t = 0; t < 4; ++t) {
      float h = hcol[t][r];
      r0 += h * h; r1 += h * p0t[t]; r2 += h * p1t[t];
    }
    #pragma unroll
    for (int mm = 1; mm < 16; mm <<= 1) {
      r0 += __shfl_xor(r0, mm); r1 += __shfl_xor(r1, mm); r2 += __shfl_xor(r2, mm);
    }
    float* row = ha + (size_t)(nb + q * 4 + r) * 68;
    #pragma unroll
    for (int t = 0; t < 4; ++t) row[t * 16 + mrow] = hcol[t][r];
    if (mrow == 0) {
      float hi = 1.f / (sqrtf(r0) + 1e-12f);
      row[64] = r1 * hi * ip0;
      row[65] = r2 * hi * ip1;
    }
  }
}

// ---------------------------------------------------------------------------
// K2 (MFMA): xl (or xr) = ha @ W + b  -> bf16 [n][256] (col j = h*64+c).
// ---------------------------------------------------------------------------
__global__ __launch_bounds__(256) void k_lin(
    const float* __restrict__ ha, const float* __restrict__ W,
    const float* __restrict__ b, u16* __restrict__ outp)
{
  __shared__ u16 wl[3 * 16 * 64 * 8];  // 48 KB
  for (int m = threadIdx.x; m < 24576; m += 256) {
    int j = m & 7, l = (m >> 3) & 63, t = (m >> 9) & 15, s = m >> 13;
    int k = s * 32 + (l >> 4) * 8 + j;
    int j2 = t * 16 + (l & 15);
    wl[m] = (k < GAT_IN) ? f2bf(W[k * 256 + j2]) : (u16)0;
  }
  __syncthreads();
  const int lane = threadIdx.x & 63;
  const int nb = blockIdx.x * 64 + (threadIdx.x >> 6) * 16;
  if (nb >= N_NODES) return;
  const int mrow = lane & 15, q = lane >> 4;

  f4v acc[16];
  #pragma unroll
  for (int t = 0; t < 16; ++t) acc[t] = (f4v){0.f, 0.f, 0.f, 0.f};

  const float* row = ha + (size_t)(nb + mrow) * 68;
  #pragma unroll
  for (int s = 0; s < 3; ++s) {
    float uu[8];
    if (s < 2) {
      float4 u0 = *(const float4*)(row + s * 32 + q * 8);
      float4 u1 = *(const float4*)(row + s * 32 + q * 8 + 4);
      uu[0]=u0.x; uu[1]=u0.y; uu[2]=u0.z; uu[3]=u0.w;
      uu[4]=u1.x; uu[5]=u1.y; uu[6]=u1.z; uu[7]=u1.w;
    } else {
      #pragma unroll
      for (int j = 0; j < 8; ++j) uu[j] = 0.f;
      if (q == 0) { uu[0] = row[64]; uu[1] = row[65]; }
    }
    s8v ah, al;
    split8(uu, ah, al);
    const u16* wp = &wl[s * 8192 + lane * 8];
    #pragma unroll
    for (int t = 0; t < 16; ++t) {
      s8v bv = *(const s8v*)(wp + t * 512);
      acc[t] = __builtin_amdgcn_mfma_f32_16x16x32_bf16(ah, bv, acc[t], 0, 0, 0);
      acc[t] = __builtin_amdgcn_mfma_f32_16x16x32_bf16(al, bv, acc[t], 0, 0, 0);
    }
  }

  #pragma unroll
  for (int t = 0; t < 16; ++t) {
    float bc = b[t * 16 + mrow];
    #pragma unroll
    for (int r = 0; r < 4; ++r) {
      outp[(size_t)(nb + q * 4 + r) * 256 + t * 16 + mrow] = f2bf(acc[t][r] + bc);
    }
  }
}

// ---------------------------------------------------------------------------
// K5: per-dst-node softmax aggregation (no max-shift: logits are O(1); clamp
// at 60 guards overflow) + head-mean + relu + classifier.
// ---------------------------------------------------------------------------
template <int INLINE_XR>
__global__ __launch_bounds__(256) void k_agg(
    const u16* __restrict__ xls, const u16* __restrict__ xrs,
    const float* __restrict__ ha, const float* __restrict__ Wr,
    const float* __restrict__ br,
    const int* __restrict__ esrc, const int* __restrict__ off,
    const float* __restrict__ att, const float* __restrict__ gbias,
    const float* __restrict__ wcls, const float* __restrict__ bcls,
    float* __restrict__ out)
{
  __shared__ u16 wr[INLINE_XR ? GAT_IN * 256 : 64];
  if (INLINE_XR) {
    for (int m = threadIdx.x; m < GAT_IN * 256; m += 256) wr[m] = f2bf(Wr[m]);
    __syncthreads();
  }
  const int lane = threadIdx.x & 63;
  const int n = blockIdx.x * 4 + (threadIdx.x >> 6);
  if (n >= N_NODES) return;

  const float4 av = *(const float4*)(att + lane * 4);

  float xr0, xr1, xr2, xr3;
  if (INLINE_XR) {
    float4 bv = *(const float4*)(br + lane * 4);
    xr0 = bv.x; xr1 = bv.y; xr2 = bv.z; xr3 = bv.w;
    const float* hrow = ha + (size_t)n * 68;
    for (int i = 0; i < GAT_IN; ++i) {
      ushort4 wv = *(const ushort4*)&wr[i * 256 + lane * 4];
      float hv = hrow[i];
      xr0 += hv * bf2f(wv.x); xr1 += hv * bf2f(wv.y);
      xr2 += hv * bf2f(wv.z); xr3 += hv * bf2f(wv.w);
    }
  } else {
    ushort4 qv = *(const ushort4*)(xrs + (size_t)n * 256 + lane * 4);
    xr0 = bf2f(qv.x); xr1 = bf2f(qv.y); xr2 = bf2f(qv.z); xr3 = bf2f(qv.w);
  }

  int kb = off[n], ke = off[n + 1];
  if (kb < 0) kb = 0;
  if (ke > N_EDGES) ke = N_EDGES;
  int deg = ke - kb; if (deg < 0) deg = 0;

  float l_ = 0.f;
  float c0 = 0.f, c1 = 0.f, c2 = 0.f, c3 = 0.f;

  int s1 = (deg > 0) ? esrc[kb] : n;
  ushort4 xc = *(const ushort4*)(xls + (size_t)n * 256 + lane * 4);  // self
  for (int i = 0; i <= deg; ++i) {
    int s2 = (i + 2 <= deg) ? esrc[kb + i + 1] : n;
    ushort4 xn = *(const ushort4*)(xls + (size_t)s1 * 256 + lane * 4);
    float x0 = bf2f(xc.x), x1 = bf2f(xc.y), x2 = bf2f(xc.z), x3 = bf2f(xc.w);
    float t0 = x0 + xr0, t1 = x1 + xr1, t2 = x2 + xr2, t3 = x3 + xr3;
    t0 = fmaxf(t0, 0.2f * t0);   // leaky relu
    t1 = fmaxf(t1, 0.2f * t1);
    t2 = fmaxf(t2, 0.2f * t2);
    t3 = fmaxf(t3, 0.2f * t3);
    float g = av.x * t0 + av.y * t1 + av.z * t2 + av.w * t3;
    g += __shfl_xor(g, 1); g += __shfl_xor(g, 2);
    g += __shfl_xor(g, 4); g += __shfl_xor(g, 8);
    float a = __expf(fminf(g, 60.f));
    l_ += a;
    c0 = fmaf(a, x0, c0); c1 = fmaf(a, x1, c1);
    c2 = fmaf(a, x2, c2); c3 = fmaf(a, x3, c3);
    xc = xn; s1 = s2;
  }

  float inv = 1.f / (l_ + 1e-16f);
  float v0 = c0 * inv, v1 = c1 * inv, v2 = c2 * inv, v3 = c3 * inv;
  v0 += __shfl_xor(v0, 16); v0 += __shfl_xor(v0, 32);
  v1 += __shfl_xor(v1, 16); v1 += __shfl_xor(v1, 32);
  v2 += __shfl_xor(v2, 16); v2 += __shfl_xor(v2, 32);
  v3 += __shfl_xor(v3, 16); v3 += __shfl_xor(v3, 32);
  const int g4 = (lane & 15) * 4;
  const int h = lane >> 4;
  float4 gb = *(const float4*)(gbias + g4);
  v0 = fmaxf(0.25f * v0 + gb.x, 0.f);
  v1 = fmaxf(0.25f * v1 + gb.y, 0.f);
  v2 = fmaxf(0.25f * v2 + gb.z, 0.f);
  v3 = fmaxf(0.25f * v3 + gb.w, 0.f);
  float4 w0 = *(const float4*)(wcls + (g4 + 0) * 16 + h * 4);
  float4 w1 = *(const float4*)(wcls + (g4 + 1) * 16 + h * 4);
  float4 w2 = *(const float4*)(wcls + (g4 + 2) * 16 + h * 4);
  float4 w3 = *(const float4*)(wcls + (g4 + 3) * 16 + h * 4);
  float o0 = v0 * w0.x + v1 * w1.x + v2 * w2.x + v3 * w3.x;
  float o1 = v0 * w0.y + v1 * w1.y + v2 * w2.y + v3 * w3.y;
  float o2 = v0 * w0.z + v1 * w1.z + v2 * w2.z + v3 * w3.z;
  float o3 = v0 * w0.w + v1 * w1.w + v2 * w2.w + v3 * w3.w;
  #pragma unroll
  for (int mm = 1; mm < 16; mm <<= 1) {
    o0 += __shfl_xor(o0, mm); o1 += __shfl_xor(o1, mm);
    o2 += __shfl_xor(o2, mm); o3 += __shfl_xor(o3, mm);
  }
  if ((lane & 15) == 0) {
    float4 bcv = *(const float4*)(bcls + h * 4);
    float4 ov;
    ov.x = o0 + bcv.x; ov.y = o1 + bcv.y; ov.z = o2 + bcv.z; ov.w = o3 + bcv.w;
    *(float4*)(out + (size_t)n * 16 + h * 4) = ov;
  }
}

// ---------------------------------------------------------------------------
extern "C" void kernel_launch(void* const* d_in, const int* in_sizes, int n_in,
                              void* d_out, int out_size, void* d_ws, size_t ws_size,
                              hipStream_t stream)
{
  const float* x     = (const float*)d_in[0];
  const void*  ei    = d_in[1];
  const float* Win   = (const float*)d_in[2];
  const float* bin   = (const float*)d_in[3];
  const float* proto = (const float*)d_in[4];
  const float* Wl    = (const float*)d_in[5];
  const float* bl    = (const float*)d_in[6];
  const float* Wr    = (const float*)d_in[7];
  const float* br    = (const float*)d_in[8];
  const float* att   = (const float*)d_in[9];
  const float* gbias = (const float*)d_in[10];
  const float* wcls  = (const float*)d_in[11];
  const float* bcls  = (const float*)d_in[12];
  float* out = (float*)d_out;

  char* p = (char*)d_ws;
  size_t used = 0;
  auto carve = [&](size_t bytes) {
    char* q = p + used;
    used += (bytes + 255) & ~(size_t)255;
    return (void*)q;
  };
  int* flag_i = (int*)carve(256);
  int* deg  = (int*)carve(N_NODES * 4);
  int* off  = (int*)carve((N_NODES + 1) * 4);
  int* cur  = (int*)carve(N_NODES * 4);
  int* bsum = (int*)carve(NB_CSR * 4);
  int* boff = (int*)carve(NB_CSR * 4);
  int* esrc = (int*)carve(N_EDGES * 4);
  float* ha = (float*)carve((size_t)N_NODES * 68 * 4 + 512);
  u16* xls  = (u16*)carve((size_t)N_NODES * 256 * 2);
  size_t used_min = used + ((size_t)N_NODES * 256 * 2);
  u16* xrs  = (u16*)carve((size_t)N_NODES * 256 * 2);
  const bool full = ws_size >= used_min;

  // cooperative CSR build (detect + hist + scan + scatter in one launch)
  {
    void* args[] = {(void*)&ei, (void*)&flag_i, (void*)&deg, (void*)&bsum,
                    (void*)&boff, (void*)&off, (void*)&cur, (void*)&esrc};
    hipLaunchCooperativeKernel((const void*)k_csr, dim3(NB_CSR), dim3(256),
                               args, 0, stream);
  }
  k_haug<<<782, 256, 0, stream>>>(x, Win, bin, proto, ha);
  k_lin<<<782, 256, 0, stream>>>(ha, Wl, bl, xls);
  if (full) k_lin<<<782, 256, 0, stream>>>(ha, Wr, br, xrs);
  if (full)
    k_agg<0><<<12500, 256, 0, stream>>>(xls, xrs, ha, Wr, br, esrc, off,
                                        att, gbias, wcls, bcls, out);
  else
    k_agg<1><<<12500, 256, 0, stream>>>(xls, xrs, ha, Wr, br, esrc, off,
                                        att, gbias, wcls, bcls, out);
}

// Round 8
// 344.957 us; speedup vs baseline: 1.4914x; 1.4914x over previous
//
#include <hip/hip_runtime.h>

#define N_NODES 50000
#define N_EDGES 800000
#define IN_DIM 256
#define HID 64
#define OUT_DIM 16
#define GAT_IN 66   // HID + N_PROTO
#define NB_SCAN 196 // 196*256 = 50176 >= N_NODES

typedef unsigned short u16;
typedef unsigned int u32;
typedef __attribute__((ext_vector_type(8))) short s8v;   // 8 bf16 (4 VGPRs)
typedef __attribute__((ext_vector_type(4))) float f4v;   // MFMA accumulator

__device__ __forceinline__ float bf2f(u16 u) {
  union { u32 i; float f; } v; v.i = ((u32)u) << 16; return v.f;
}
__device__ __forceinline__ u16 f2bf(float f) {
  union { float f; u32 i; } v; v.f = f;
  u32 r = v.i + 0x7FFFu + ((v.i >> 16) & 1u);
  return (u16)(r >> 16);
}
__device__ __forceinline__ void split8(const float* uu, s8v& ah, s8v& al) {
  #pragma unroll
  for (int j = 0; j < 8; ++j) {
    u32 bits = __float_as_uint(uu[j]);
    u16 hb = (u16)(bits >> 16);
    ah[j] = (short)hb;
    al[j] = (short)f2bf(uu[j] - bf2f(hb));
  }
}

// ---------------------------------------------------------------------------
// K0: zero deg[]; detect int dtype of edge_index (int64 vs int32).
// ---------------------------------------------------------------------------
__global__ void k_detect(const void* __restrict__ ei, int* __restrict__ flag_i,
                         int* __restrict__ deg) {
  int i = blockIdx.x * 256 + threadIdx.x;
  if (i < N_NODES) deg[i] = 0;
  if (blockIdx.x == 0 && threadIdx.x == 0) {
    const long long* e64 = (const long long*)ei;
    int ok = 1;
    for (int k = 0; k < 64; k++) {
      long long v = e64[k];
      if (v < 0 || v >= N_NODES) { ok = 0; break; }
    }
    *flag_i = ok;
  }
}

// ---------------------------------------------------------------------------
// K1 (MFMA): h = relu(x @ W_in + b_in); sem = cosine sim vs prototypes.
// 512 threads = 8 waves, each wave one 16-node M-tile (128 nodes/block).
// W_in staged bf16 in LDS via COALESCED float4 loads + inverse permutation:
// dest m = s*2048 + t*512 + l*8 + j  <-  src w = k*64+c,
//   k = s*32+(l>>4)*8+j, c = t*16+(l&15).
// ---------------------------------------------------------------------------
__global__ __launch_bounds__(512) void k_haug(
    const float* __restrict__ x, const float* __restrict__ Win,
    const float* __restrict__ bin, const float* __restrict__ proto,
    float* __restrict__ ha)
{
  __shared__ u16 wb[8 * 4 * 64 * 8];  // 32 KB
  for (int w4 = threadIdx.x; w4 < 4096; w4 += 512) {
    int w = w4 * 4;
    float4 v = *(const float4*)(Win + w);
    int k = w >> 6, c0 = w & 63;
    int s = k >> 5, r5 = k & 31;
    int lh = r5 >> 3, j = r5 & 7;
    int t = c0 >> 4, l15 = c0 & 15;  // c0%16 in {0,4,8,12}: t,j fixed across 4
    int m = s * 2048 + t * 512 + (lh * 16 + l15) * 8 + j;
    wb[m]      = f2bf(v.x);
    wb[m + 8]  = f2bf(v.y);
    wb[m + 16] = f2bf(v.z);
    wb[m + 24] = f2bf(v.w);
  }
  __syncthreads();
  const int lane = threadIdx.x & 63;
  const int nb = blockIdx.x * 128 + (threadIdx.x >> 6) * 16;
  if (nb >= N_NODES) return;
  const int mrow = lane & 15, q = lane >> 4;

  f4v acc0 = {0.f,0.f,0.f,0.f}, acc1 = {0.f,0.f,0.f,0.f};
  f4v acc2 = {0.f,0.f,0.f,0.f}, acc3 = {0.f,0.f,0.f,0.f};
  const float* xrow = x + (size_t)(nb + mrow) * IN_DIM + q * 8;
  #pragma unroll 2
  for (int s = 0; s < 8; ++s) {
    float4 u0 = *(const float4*)(xrow + s * 32);
    float4 u1 = *(const float4*)(xrow + s * 32 + 4);
    float uu[8] = {u0.x, u0.y, u0.z, u0.w, u1.x, u1.y, u1.z, u1.w};
    s8v ah, al;
    split8(uu, ah, al);
    const u16* wp = &wb[s * 2048 + lane * 8];
    s8v b0 = *(const s8v*)(wp);
    s8v b1 = *(const s8v*)(wp + 512);
    s8v b2 = *(const s8v*)(wp + 1024);
    s8v b3 = *(const s8v*)(wp + 1536);
    acc0 = __builtin_amdgcn_mfma_f32_16x16x32_bf16(ah, b0, acc0, 0, 0, 0);
    acc0 = __builtin_amdgcn_mfma_f32_16x16x32_bf16(al, b0, acc0, 0, 0, 0);
    acc1 = __builtin_amdgcn_mfma_f32_16x16x32_bf16(ah, b1, acc1, 0, 0, 0);
    acc1 = __builtin_amdgcn_mfma_f32_16x16x32_bf16(al, b1, acc1, 0, 0, 0);
    acc2 = __builtin_amdgcn_mfma_f32_16x16x32_bf16(ah, b2, acc2, 0, 0, 0);
    acc2 = __builtin_amdgcn_mfma_f32_16x16x32_bf16(al, b2, acc2, 0, 0, 0);
    acc3 = __builtin_amdgcn_mfma_f32_16x16x32_bf16(ah, b3, acc3, 0, 0, 0);
    acc3 = __builtin_amdgcn_mfma_f32_16x16x32_bf16(al, b3, acc3, 0, 0, 0);
  }

  float bt[4], p0t[4], p1t[4];
  #pragma unroll
  for (int t = 0; t < 4; ++t) {
    bt[t]  = bin[t * 16 + mrow];
    p0t[t] = proto[t * 16 + mrow];
    p1t[t] = proto[64 + t * 16 + mrow];
  }
  float np0 = 0.f, np1 = 0.f;
  #pragma unroll
  for (int t = 0; t < 4; ++t) { np0 += p0t[t] * p0t[t]; np1 += p1t[t] * p1t[t]; }
  #pragma unroll
  for (int mm = 1; mm < 16; mm <<= 1) {
    np0 += __shfl_xor(np0, mm); np1 += __shfl_xor(np1, mm);
  }
  const float ip0 = 1.f / (sqrtf(np0) + 1e-12f);
  const float ip1 = 1.f / (sqrtf(np1) + 1e-12f);

  float hcol[4][4];
  #pragma unroll
  for (int r = 0; r < 4; ++r) {
    hcol[0][r] = fmaxf(acc0[r] + bt[0], 0.f);
    hcol[1][r] = fmaxf(acc1[r] + bt[1], 0.f);
    hcol[2][r] = fmaxf(acc2[r] + bt[2], 0.f);
    hcol[3][r] = fmaxf(acc3[r] + bt[3], 0.f);
  }
  #pragma unroll
  for (int r = 0; r < 4; ++r) {
    float r0 = 0.f, r1 = 0.f, r2 = 0.f;
    #pragma unroll
    for (int t = 0; t < 4; ++t) {
      float h = hcol[t][r];
      r0 += h * h; r1 += h * p0t[t]; r2 += h * p1t[t];
    }
    #pragma unroll
    for (int mm = 1; mm < 16; mm <<= 1) {
      r0 += __shfl_xor(r0, mm); r1 += __shfl_xor(r1, mm); r2 += __shfl_xor(r2, mm);
    }
    float* row = ha + (size_t)(nb + q * 4 + r) * 68;
    #pragma unroll
    for (int t = 0; t < 4; ++t) row[t * 16 + mrow] = hcol[t][r];
    if (mrow == 0) {
      float hi = 1.f / (sqrtf(r0) + 1e-12f);
      row[64] = r1 * hi * ip0;
      row[65] = r2 * hi * ip1;
    }
  }
}

// ---------------------------------------------------------------------------
// K2 (MFMA): xl (or xr) = ha @ W + b  -> bf16 [n][256] (col j = h*64+c).
// 512 threads = 8 waves x one 16-node tile. Coalesced staging, K pad 66->96.
// dest m = s*8192 + t*512 + l*8 + j  <-  src w = k*256+j2,
//   k = s*32+(l>>4)*8+j, j2 = t*16+(l&15).
// ---------------------------------------------------------------------------
__global__ __launch_bounds__(512) void k_lin(
    const float* __restrict__ ha, const float* __restrict__ W,
    const float* __restrict__ b, u16* __restrict__ outp)
{
  __shared__ u16 wl[3 * 16 * 64 * 8];  // 48 KB
  // zero the s=2 K-step (k in [64,96)), then overwrite k=64,65 in the fill
  for (int i = threadIdx.x; i < 4096; i += 512) ((u32*)wl)[8192 + i] = 0;
  __syncthreads();
  for (int w4 = threadIdx.x; w4 < 4224; w4 += 512) {  // 16896/4
    int w = w4 * 4;
    float4 v = *(const float4*)(W + w);
    int k = w >> 8, j2 = w & 255;
    int s = k >> 5, r5 = k & 31;
    int lh = r5 >> 3, j = r5 & 7;
    int t = j2 >> 4, l15 = j2 & 15;  // j2%16 in {0,4,8,12}: t,j fixed across 4
    int m = s * 8192 + t * 512 + (lh * 16 + l15) * 8 + j;
    wl[m]      = f2bf(v.x);
    wl[m + 8]  = f2bf(v.y);
    wl[m + 16] = f2bf(v.z);
    wl[m + 24] = f2bf(v.w);
  }
  __syncthreads();
  const int lane = threadIdx.x & 63;
  const int nb = blockIdx.x * 128 + (threadIdx.x >> 6) * 16;
  if (nb >= N_NODES) return;
  const int mrow = lane & 15, q = lane >> 4;

  f4v acc[16];
  #pragma unroll
  for (int t = 0; t < 16; ++t) acc[t] = (f4v){0.f, 0.f, 0.f, 0.f};

  const float* row = ha + (size_t)(nb + mrow) * 68;
  #pragma unroll
  for (int s = 0; s < 3; ++s) {
    float uu[8];
    if (s < 2) {
      float4 u0 = *(const float4*)(row + s * 32 + q * 8);
      float4 u1 = *(const float4*)(row + s * 32 + q * 8 + 4);
      uu[0]=u0.x; uu[1]=u0.y; uu[2]=u0.z; uu[3]=u0.w;
      uu[4]=u1.x; uu[5]=u1.y; uu[6]=u1.z; uu[7]=u1.w;
    } else {
      #pragma unroll
      for (int j = 0; j < 8; ++j) uu[j] = 0.f;
      if (q == 0) { uu[0] = row[64]; uu[1] = row[65]; }
    }
    s8v ah, al;
    split8(uu, ah, al);
    const u16* wp = &wl[s * 8192 + lane * 8];
    #pragma unroll
    for (int t = 0; t < 16; ++t) {
      s8v bv = *(const s8v*)(wp + t * 512);
      acc[t] = __builtin_amdgcn_mfma_f32_16x16x32_bf16(ah, bv, acc[t], 0, 0, 0);
      acc[t] = __builtin_amdgcn_mfma_f32_16x16x32_bf16(al, bv, acc[t], 0, 0, 0);
    }
  }

  #pragma unroll
  for (int t = 0; t < 16; ++t) {
    float bc = b[t * 16 + mrow];
    #pragma unroll
    for (int r = 0; r < 4; ++r) {
      outp[(size_t)(nb + q * 4 + r) * 256 + t * 16 + mrow] = f2bf(acc[t][r] + bc);
    }
  }
}

// --------------------------- CSR construction ------------------------------
__global__ void k_hist(const void* __restrict__ ei, const int* __restrict__ flag_i,
                       int* __restrict__ deg) {
  int e = blockIdx.x * 256 + threadIdx.x;
  if (e >= N_EDGES) return;
  int d;
  if (*flag_i) d = (int)((const long long*)ei)[N_EDGES + e];
  else         d = ((const int*)ei)[N_EDGES + e];
  if ((unsigned)d < N_NODES) atomicAdd(&deg[d], 1);
}

__global__ __launch_bounds__(256) void k_scan_a(
    const int* __restrict__ deg, int* __restrict__ bsum)
{
  int i = blockIdx.x * 256 + threadIdx.x;
  int v = (i < N_NODES) ? deg[i] : 0;
  #pragma unroll
  for (int d = 1; d < 64; d <<= 1) v += __shfl_xor(v, d);
  __shared__ int wsum[4];
  if ((threadIdx.x & 63) == 0) wsum[threadIdx.x >> 6] = v;
  __syncthreads();
  if (threadIdx.x == 0)
    bsum[blockIdx.x] = wsum[0] + wsum[1] + wsum[2] + wsum[3];
}

__global__ __launch_bounds__(256) void k_scan_b(
    const int* __restrict__ bsum, int* __restrict__ boff)
{
  const int t = threadIdx.x;
  const int lane = t & 63;
  int v = (t < NB_SCAN) ? bsum[t] : 0;
  int inc = v;
  #pragma unroll
  for (int d = 1; d < 64; d <<= 1) {
    int sv = __shfl_up(inc, d);
    if (lane >= d) inc += sv;
  }
  __shared__ int wtot[4];
  if (lane == 63) wtot[t >> 6] = inc;
  __syncthreads();
  int add = 0;
  for (int w = 0; w < (t >> 6); ++w) add += wtot[w];
  if (t < NB_SCAN) boff[t] = add + inc - v;
}

__global__ __launch_bounds__(256) void k_scan_c(
    const int* __restrict__ deg, const int* __restrict__ boff,
    int* __restrict__ off, int* __restrict__ cur)
{
  const int t = threadIdx.x;
  const int lane = t & 63;
  int i = blockIdx.x * 256 + t;
  int v = (i < N_NODES) ? deg[i] : 0;
  int inc = v;
  #pragma unroll
  for (int d = 1; d < 64; d <<= 1) {
    int sv = __shfl_up(inc, d);
    if (lane >= d) inc += sv;
  }
  __shared__ int wtot[4];
  if (lane == 63) wtot[t >> 6] = inc;
  __syncthreads();
  int add = boff[blockIdx.x];
  for (int w = 0; w < (t >> 6); ++w) add += wtot[w];
  int ex = add + inc - v;
  if (i < N_NODES) { off[i] = ex; cur[i] = ex; }
  if (i == N_NODES - 1) off[N_NODES] = ex + v;
}

__global__ void k_scatter(const void* __restrict__ ei, const int* __restrict__ flag_i,
                          int* __restrict__ cur, int* __restrict__ esrc) {
  int e = blockIdx.x * 256 + threadIdx.x;
  if (e >= N_EDGES) return;
  int s, d;
  if (*flag_i) {
    s = (int)((const long long*)ei)[e];
    d = (int)((const long long*)ei)[N_EDGES + e];
  } else {
    s = ((const int*)ei)[e];
    d = ((const int*)ei)[N_EDGES + e];
  }
  if ((unsigned)d >= N_NODES) return;
  if ((unsigned)s >= N_NODES) s = 0;
  int p = atomicAdd(&cur[d], 1);
  if ((unsigned)p < N_EDGES) esrc[p] = s;
}

// ---------------------------------------------------------------------------
// K5: per-dst-node softmax aggregation (no max-shift; clamp 60) + head-mean
// + relu + classifier. Head-major lane = (h=lane>>4, c4=(lane&15)*4).
// ---------------------------------------------------------------------------
template <int INLINE_XR>
__global__ __launch_bounds__(256) void k_agg(
    const u16* __restrict__ xls, const u16* __restrict__ xrs,
    const float* __restrict__ ha, const float* __restrict__ Wr,
    const float* __restrict__ br,
    const int* __restrict__ esrc, const int* __restrict__ off,
    const float* __restrict__ att, const float* __restrict__ gbias,
    const float* __restrict__ wcls, const float* __restrict__ bcls,
    float* __restrict__ out)
{
  __shared__ u16 wr[INLINE_XR ? GAT_IN * 256 : 64];
  if (INLINE_XR) {
    for (int m = threadIdx.x; m < GAT_IN * 256; m += 256) wr[m] = f2bf(Wr[m]);
    __syncthreads();
  }
  const int lane = threadIdx.x & 63;
  const int n = blockIdx.x * 4 + (threadIdx.x >> 6);
  if (n >= N_NODES) return;

  const float4 av = *(const float4*)(att + lane * 4);

  float xr0, xr1, xr2, xr3;
  if (INLINE_XR) {
    float4 bv = *(const float4*)(br + lane * 4);
    xr0 = bv.x; xr1 = bv.y; xr2 = bv.z; xr3 = bv.w;
    const float* hrow = ha + (size_t)n * 68;
    for (int i = 0; i < GAT_IN; ++i) {
      ushort4 wv = *(const ushort4*)&wr[i * 256 + lane * 4];
      float hv = hrow[i];
      xr0 += hv * bf2f(wv.x); xr1 += hv * bf2f(wv.y);
      xr2 += hv * bf2f(wv.z); xr3 += hv * bf2f(wv.w);
    }
  } else {
    ushort4 qv = *(const ushort4*)(xrs + (size_t)n * 256 + lane * 4);
    xr0 = bf2f(qv.x); xr1 = bf2f(qv.y); xr2 = bf2f(qv.z); xr3 = bf2f(qv.w);
  }

  int kb = off[n], ke = off[n + 1];
  if (kb < 0) kb = 0;
  if (ke > N_EDGES) ke = N_EDGES;
  int deg = ke - kb; if (deg < 0) deg = 0;

  float l_ = 0.f;
  float c0 = 0.f, c1 = 0.f, c2 = 0.f, c3 = 0.f;

  int s1 = (deg > 0) ? esrc[kb] : n;
  ushort4 xc = *(const ushort4*)(xls + (size_t)n * 256 + lane * 4);  // self
  for (int i = 0; i <= deg; ++i) {
    int s2 = (i + 2 <= deg) ? esrc[kb + i + 1] : n;
    ushort4 xn = *(const ushort4*)(xls + (size_t)s1 * 256 + lane * 4);
    float x0 = bf2f(xc.x), x1 = bf2f(xc.y), x2 = bf2f(xc.z), x3 = bf2f(xc.w);
    float t0 = x0 + xr0, t1 = x1 + xr1, t2 = x2 + xr2, t3 = x3 + xr3;
    t0 = fmaxf(t0, 0.2f * t0);
    t1 = fmaxf(t1, 0.2f * t1);
    t2 = fmaxf(t2, 0.2f * t2);
    t3 = fmaxf(t3, 0.2f * t3);
    float g = av.x * t0 + av.y * t1 + av.z * t2 + av.w * t3;
    g += __shfl_xor(g, 1); g += __shfl_xor(g, 2);
    g += __shfl_xor(g, 4); g += __shfl_xor(g, 8);
    float a = __expf(fminf(g, 60.f));
    l_ += a;
    c0 = fmaf(a, x0, c0); c1 = fmaf(a, x1, c1);
    c2 = fmaf(a, x2, c2); c3 = fmaf(a, x3, c3);
    xc = xn; s1 = s2;
  }

  float inv = 1.f / (l_ + 1e-16f);
  float v0 = c0 * inv, v1 = c1 * inv, v2 = c2 * inv, v3 = c3 * inv;
  v0 += __shfl_xor(v0, 16); v0 += __shfl_xor(v0, 32);
  v1 += __shfl_xor(v1, 16); v1 += __shfl_xor(v1, 32);
  v2 += __shfl_xor(v2, 16); v2 += __shfl_xor(v2, 32);
  v3 += __shfl_xor(v3, 16); v3 += __shfl_xor(v3, 32);
  const int g4 = (lane & 15) * 4;
  const int h = lane >> 4;
  float4 gb = *(const float4*)(gbias + g4);
  v0 = fmaxf(0.25f * v0 + gb.x, 0.f);
  v1 = fmaxf(0.25f * v1 + gb.y, 0.f);
  v2 = fmaxf(0.25f * v2 + gb.z, 0.f);
  v3 = fmaxf(0.25f * v3 + gb.w, 0.f);
  float4 w0 = *(const float4*)(wcls + (g4 + 0) * 16 + h * 4);
  float4 w1 = *(const float4*)(wcls + (g4 + 1) * 16 + h * 4);
  float4 w2 = *(const float4*)(wcls + (g4 + 2) * 16 + h * 4);
  float4 w3 = *(const float4*)(wcls + (g4 + 3) * 16 + h * 4);
  float o0 = v0 * w0.x + v1 * w1.x + v2 * w2.x + v3 * w3.x;
  float o1 = v0 * w0.y + v1 * w1.y + v2 * w2.y + v3 * w3.y;
  float o2 = v0 * w0.z + v1 * w1.z + v2 * w2.z + v3 * w3.z;
  float o3 = v0 * w0.w + v1 * w1.w + v2 * w2.w + v3 * w3.w;
  #pragma unroll
  for (int mm = 1; mm < 16; mm <<= 1) {
    o0 += __shfl_xor(o0, mm); o1 += __shfl_xor(o1, mm);
    o2 += __shfl_xor(o2, mm); o3 += __shfl_xor(o3, mm);
  }
  if ((lane & 15) == 0) {
    float4 bcv = *(const float4*)(bcls + h * 4);
    float4 ov;
    ov.x = o0 + bcv.x; ov.y = o1 + bcv.y; ov.z = o2 + bcv.z; ov.w = o3 + bcv.w;
    *(float4*)(out + (size_t)n * 16 + h * 4) = ov;
  }
}

// ---------------------------------------------------------------------------
extern "C" void kernel_launch(void* const* d_in, const int* in_sizes, int n_in,
                              void* d_out, int out_size, void* d_ws, size_t ws_size,
                              hipStream_t stream)
{
  const float* x     = (const float*)d_in[0];
  const void*  ei    = d_in[1];
  const float* Win   = (const float*)d_in[2];
  const float* bin   = (const float*)d_in[3];
  const float* proto = (const float*)d_in[4];
  const float* Wl    = (const float*)d_in[5];
  const float* bl    = (const float*)d_in[6];
  const float* Wr    = (const float*)d_in[7];
  const float* br    = (const float*)d_in[8];
  const float* att   = (const float*)d_in[9];
  const float* gbias = (const float*)d_in[10];
  const float* wcls  = (const float*)d_in[11];
  const float* bcls  = (const float*)d_in[12];
  float* out = (float*)d_out;

  char* p = (char*)d_ws;
  size_t used = 0;
  auto carve = [&](size_t bytes) {
    char* q = p + used;
    used += (bytes + 255) & ~(size_t)255;
    return (void*)q;
  };
  int* flag_i = (int*)carve(256);
  int* deg  = (int*)carve(N_NODES * 4);
  int* off  = (int*)carve((N_NODES + 1) * 4);
  int* cur  = (int*)carve(N_NODES * 4);
  int* bsum = (int*)carve(NB_SCAN * 4);
  int* boff = (int*)carve(NB_SCAN * 4);
  int* esrc = (int*)carve(N_EDGES * 4);
  float* ha = (float*)carve((size_t)N_NODES * 68 * 4 + 512);
  u16* xls  = (u16*)carve((size_t)N_NODES * 256 * 2);
  size_t used_min = used + ((size_t)N_NODES * 256 * 2);
  u16* xrs  = (u16*)carve((size_t)N_NODES * 256 * 2);
  const bool full = ws_size >= used_min;

  k_detect<<<196, 256, 0, stream>>>(ei, flag_i, deg);
  k_haug<<<391, 512, 0, stream>>>(x, Win, bin, proto, ha);
  k_hist<<<3125, 256, 0, stream>>>(ei, flag_i, deg);
  k_lin<<<391, 512, 0, stream>>>(ha, Wl, bl, xls);
  if (full) k_lin<<<391, 512, 0, stream>>>(ha, Wr, br, xrs);
  k_scan_a<<<NB_SCAN, 256, 0, stream>>>(deg, bsum);
  k_scan_b<<<1, 256, 0, stream>>>(bsum, boff);
  k_scan_c<<<NB_SCAN, 256, 0, stream>>>(deg, boff, off, cur);
  k_scatter<<<3125, 256, 0, stream>>>(ei, flag_i, cur, esrc);
  if (full)
    k_agg<0><<<12500, 256, 0, stream>>>(xls, xrs, ha, Wr, br, esrc, off,
                                        att, gbias, wcls, bcls, out);
  else
    k_agg<1><<<12500, 256, 0, stream>>>(xls, xrs, ha, Wr, br, esrc, off,
                                        att, gbias, wcls, bcls, out);
}

// Round 9
// 323.246 us; speedup vs baseline: 1.5915x; 1.0672x over previous
//
#include <hip/hip_runtime.h>

#define N_NODES 50000
#define N_EDGES 800000
#define IN_DIM 256
#define HID 64
#define OUT_DIM 16
#define GAT_IN 66   // HID + N_PROTO
#define NB_SCAN 196 // 196*256 = 50176 >= N_NODES

typedef unsigned short u16;
typedef unsigned int u32;
typedef __attribute__((ext_vector_type(8))) short s8v;   // 8 bf16 (4 VGPRs)
typedef __attribute__((ext_vector_type(4))) float f4v;   // MFMA accumulator

__device__ __forceinline__ float bf2f(u16 u) {
  union { u32 i; float f; } v; v.i = ((u32)u) << 16; return v.f;
}
__device__ __forceinline__ u16 f2bf(float f) {
  union { float f; u32 i; } v; v.f = f;
  u32 r = v.i + 0x7FFFu + ((v.i >> 16) & 1u);
  return (u16)(r >> 16);
}
__device__ __forceinline__ void split8(const float* uu, s8v& ah, s8v& al) {
  #pragma unroll
  for (int j = 0; j < 8; ++j) {
    u32 bits = __float_as_uint(uu[j]);
    u16 hb = (u16)(bits >> 16);
    ah[j] = (short)hb;
    al[j] = (short)f2bf(uu[j] - bf2f(hb));
  }
}

// ---------------------------------------------------------------------------
// K1 (MFMA): h = relu(x @ W_in + b_in); sem = cosine sim vs prototypes.
// Prologue zeroes deg[] and gcount (consumed by later CSR kernels).
// 512 threads = 8 waves, each wave one 16-node M-tile (128 nodes/block).
// W_in staged bf16 in LDS via coalesced float4 loads + inverse permutation.
// ---------------------------------------------------------------------------
__global__ __launch_bounds__(512) void k_haug(
    const float* __restrict__ x, const float* __restrict__ Win,
    const float* __restrict__ bin, const float* __restrict__ proto,
    float* __restrict__ ha, int* __restrict__ deg, int* __restrict__ gcount)
{
  for (int i = blockIdx.x * 512 + threadIdx.x; i < N_NODES; i += gridDim.x * 512)
    deg[i] = 0;
  if (blockIdx.x == 0 && threadIdx.x == 0) *gcount = 0;

  __shared__ u16 wb[8 * 4 * 64 * 8];  // 32 KB
  for (int w4 = threadIdx.x; w4 < 4096; w4 += 512) {
    int w = w4 * 4;
    float4 v = *(const float4*)(Win + w);
    int k = w >> 6, c0 = w & 63;
    int s = k >> 5, r5 = k & 31;
    int lh = r5 >> 3, j = r5 & 7;
    int t = c0 >> 4, l15 = c0 & 15;
    int m = s * 2048 + t * 512 + (lh * 16 + l15) * 8 + j;
    wb[m]      = f2bf(v.x);
    wb[m + 8]  = f2bf(v.y);
    wb[m + 16] = f2bf(v.z);
    wb[m + 24] = f2bf(v.w);
  }
  __syncthreads();
  const int lane = threadIdx.x & 63;
  const int nb = blockIdx.x * 128 + (threadIdx.x >> 6) * 16;
  if (nb >= N_NODES) return;
  const int mrow = lane & 15, q = lane >> 4;

  f4v acc0 = {0.f,0.f,0.f,0.f}, acc1 = {0.f,0.f,0.f,0.f};
  f4v acc2 = {0.f,0.f,0.f,0.f}, acc3 = {0.f,0.f,0.f,0.f};
  const float* xrow = x + (size_t)(nb + mrow) * IN_DIM + q * 8;
  #pragma unroll 2
  for (int s = 0; s < 8; ++s) {
    float4 u0 = *(const float4*)(xrow + s * 32);
    float4 u1 = *(const float4*)(xrow + s * 32 + 4);
    float uu[8] = {u0.x, u0.y, u0.z, u0.w, u1.x, u1.y, u1.z, u1.w};
    s8v ah, al;
    split8(uu, ah, al);
    const u16* wp = &wb[s * 2048 + lane * 8];
    s8v b0 = *(const s8v*)(wp);
    s8v b1 = *(const s8v*)(wp + 512);
    s8v b2 = *(const s8v*)(wp + 1024);
    s8v b3 = *(const s8v*)(wp + 1536);
    acc0 = __builtin_amdgcn_mfma_f32_16x16x32_bf16(ah, b0, acc0, 0, 0, 0);
    acc0 = __builtin_amdgcn_mfma_f32_16x16x32_bf16(al, b0, acc0, 0, 0, 0);
    acc1 = __builtin_amdgcn_mfma_f32_16x16x32_bf16(ah, b1, acc1, 0, 0, 0);
    acc1 = __builtin_amdgcn_mfma_f32_16x16x32_bf16(al, b1, acc1, 0, 0, 0);
    acc2 = __builtin_amdgcn_mfma_f32_16x16x32_bf16(ah, b2, acc2, 0, 0, 0);
    acc2 = __builtin_amdgcn_mfma_f32_16x16x32_bf16(al, b2, acc2, 0, 0, 0);
    acc3 = __builtin_amdgcn_mfma_f32_16x16x32_bf16(ah, b3, acc3, 0, 0, 0);
    acc3 = __builtin_amdgcn_mfma_f32_16x16x32_bf16(al, b3, acc3, 0, 0, 0);
  }

  float bt[4], p0t[4], p1t[4];
  #pragma unroll
  for (int t = 0; t < 4; ++t) {
    bt[t]  = bin[t * 16 + mrow];
    p0t[t] = proto[t * 16 + mrow];
    p1t[t] = proto[64 + t * 16 + mrow];
  }
  float np0 = 0.f, np1 = 0.f;
  #pragma unroll
  for (int t = 0; t < 4; ++t) { np0 += p0t[t] * p0t[t]; np1 += p1t[t] * p1t[t]; }
  #pragma unroll
  for (int mm = 1; mm < 16; mm <<= 1) {
    np0 += __shfl_xor(np0, mm); np1 += __shfl_xor(np1, mm);
  }
  const float ip0 = 1.f / (sqrtf(np0) + 1e-12f);
  const float ip1 = 1.f / (sqrtf(np1) + 1e-12f);

  float hcol[4][4];
  #pragma unroll
  for (int r = 0; r < 4; ++r) {
    hcol[0][r] = fmaxf(acc0[r] + bt[0], 0.f);
    hcol[1][r] = fmaxf(acc1[r] + bt[1], 0.f);
    hcol[2][r] = fmaxf(acc2[r] + bt[2], 0.f);
    hcol[3][r] = fmaxf(acc3[r] + bt[3], 0.f);
  }
  #pragma unroll
  for (int r = 0; r < 4; ++r) {
    float r0 = 0.f, r1 = 0.f, r2 = 0.f;
    #pragma unroll
    for (int t = 0; t < 4; ++t) {
      float h = hcol[t][r];
      r0 += h * h; r1 += h * p0t[t]; r2 += h * p1t[t];
    }
    #pragma unroll
    for (int mm = 1; mm < 16; mm <<= 1) {
      r0 += __shfl_xor(r0, mm); r1 += __shfl_xor(r1, mm); r2 += __shfl_xor(r2, mm);
    }
    float* row = ha + (size_t)(nb + q * 4 + r) * 68;
    #pragma unroll
    for (int t = 0; t < 4; ++t) row[t * 16 + mrow] = hcol[t][r];
    if (mrow == 0) {
      float hi = 1.f / (sqrtf(r0) + 1e-12f);
      row[64] = r1 * hi * ip0;
      row[65] = r2 * hi * ip1;
    }
  }
}

// ---------------------------------------------------------------------------
// K2 (MFMA): xl (or xr) = ha @ W + b  -> bf16 [n][256] (col j = h*64+c).
// ---------------------------------------------------------------------------
__global__ __launch_bounds__(512) void k_lin(
    const float* __restrict__ ha, const float* __restrict__ W,
    const float* __restrict__ b, u16* __restrict__ outp)
{
  __shared__ u16 wl[3 * 16 * 64 * 8];  // 48 KB
  for (int i = threadIdx.x; i < 4096; i += 512) ((u32*)wl)[8192 + i] = 0;
  __syncthreads();
  for (int w4 = threadIdx.x; w4 < 4224; w4 += 512) {
    int w = w4 * 4;
    float4 v = *(const float4*)(W + w);
    int k = w >> 8, j2 = w & 255;
    int s = k >> 5, r5 = k & 31;
    int lh = r5 >> 3, j = r5 & 7;
    int t = j2 >> 4, l15 = j2 & 15;
    int m = s * 8192 + t * 512 + (lh * 16 + l15) * 8 + j;
    wl[m]      = f2bf(v.x);
    wl[m + 8]  = f2bf(v.y);
    wl[m + 16] = f2bf(v.z);
    wl[m + 24] = f2bf(v.w);
  }
  __syncthreads();
  const int lane = threadIdx.x & 63;
  const int nb = blockIdx.x * 128 + (threadIdx.x >> 6) * 16;
  if (nb >= N_NODES) return;
  const int mrow = lane & 15, q = lane >> 4;

  f4v acc[16];
  #pragma unroll
  for (int t = 0; t < 16; ++t) acc[t] = (f4v){0.f, 0.f, 0.f, 0.f};

  const float* row = ha + (size_t)(nb + mrow) * 68;
  #pragma unroll
  for (int s = 0; s < 3; ++s) {
    float uu[8];
    if (s < 2) {
      float4 u0 = *(const float4*)(row + s * 32 + q * 8);
      float4 u1 = *(const float4*)(row + s * 32 + q * 8 + 4);
      uu[0]=u0.x; uu[1]=u0.y; uu[2]=u0.z; uu[3]=u0.w;
      uu[4]=u1.x; uu[5]=u1.y; uu[6]=u1.z; uu[7]=u1.w;
    } else {
      #pragma unroll
      for (int j = 0; j < 8; ++j) uu[j] = 0.f;
      if (q == 0) { uu[0] = row[64]; uu[1] = row[65]; }
    }
    s8v ah, al;
    split8(uu, ah, al);
    const u16* wp = &wl[s * 8192 + lane * 8];
    #pragma unroll
    for (int t = 0; t < 16; ++t) {
      s8v bv = *(const s8v*)(wp + t * 512);
      acc[t] = __builtin_amdgcn_mfma_f32_16x16x32_bf16(ah, bv, acc[t], 0, 0, 0);
      acc[t] = __builtin_amdgcn_mfma_f32_16x16x32_bf16(al, bv, acc[t], 0, 0, 0);
    }
  }

  #pragma unroll
  for (int t = 0; t < 16; ++t) {
    float bc = b[t * 16 + mrow];
    #pragma unroll
    for (int r = 0; r < 4; ++r) {
      outp[(size_t)(nb + q * 4 + r) * 256 + t * 16 + mrow] = f2bf(acc[t][r] + bc);
    }
  }
}

// --------------------------- CSR construction ------------------------------
// per-block int64-vs-int32 probe: int32 data read as int64 pairs has the
// second id in the high word -> value >= 2^32 -> out of range.
__device__ __forceinline__ int probe_i64(const void* ei) {
  const long long* e64 = (const long long*)ei;
  int ok = 1;
  #pragma unroll
  for (int k = 0; k < 16; k++) {
    long long v = e64[k];
    if (v < 0 || v >= N_NODES) { ok = 0; break; }
  }
  return ok;
}

__global__ void k_hist(const void* __restrict__ ei, int* __restrict__ deg) {
  __shared__ int isl_s;
  if (threadIdx.x == 0) isl_s = probe_i64(ei);
  __syncthreads();
  int e = blockIdx.x * 256 + threadIdx.x;
  if (e >= N_EDGES) return;
  int d;
  if (isl_s) d = (int)((const long long*)ei)[N_EDGES + e];
  else       d = ((const int*)ei)[N_EDGES + e];
  if ((unsigned)d < N_NODES) atomicAdd(&deg[d], 1);
}

// single-pass scan: block-local scan + atomic chunk reservation -> beg/end/cur
__global__ __launch_bounds__(256) void k_scan1(
    const int* __restrict__ deg, int* __restrict__ gcount,
    int* __restrict__ beg, int* __restrict__ end, int* __restrict__ cur)
{
  const int t = threadIdx.x;
  const int lane = t & 63;
  const int i = blockIdx.x * 256 + t;
  int v = (i < N_NODES) ? deg[i] : 0;
  int inc = v;
  #pragma unroll
  for (int d = 1; d < 64; d <<= 1) {
    int sv = __shfl_up(inc, d);
    if (lane >= d) inc += sv;
  }
  __shared__ int wtot[4];
  __shared__ int base_s;
  if (lane == 63) wtot[t >> 6] = inc;
  __syncthreads();
  if (t == 0) {
    int tot = wtot[0] + wtot[1] + wtot[2] + wtot[3];
    base_s = atomicAdd(gcount, tot);
  }
  __syncthreads();
  int add = base_s;
  for (int w = 0; w < (t >> 6); ++w) add += wtot[w];
  int ex = add + inc - v;
  if (i < N_NODES) { beg[i] = ex; cur[i] = ex; end[i] = ex + v; }
}

__global__ void k_scatter(const void* __restrict__ ei,
                          int* __restrict__ cur, int* __restrict__ esrc) {
  __shared__ int isl_s;
  if (threadIdx.x == 0) isl_s = probe_i64(ei);
  __syncthreads();
  int e = blockIdx.x * 256 + threadIdx.x;
  if (e >= N_EDGES) return;
  int s, d;
  if (isl_s) {
    s = (int)((const long long*)ei)[e];
    d = (int)((const long long*)ei)[N_EDGES + e];
  } else {
    s = ((const int*)ei)[e];
    d = ((const int*)ei)[N_EDGES + e];
  }
  if ((unsigned)d >= N_NODES) return;
  if ((unsigned)s >= N_NODES) s = 0;
  int p = atomicAdd(&cur[d], 1);
  if ((unsigned)p < N_EDGES) esrc[p] = s;
}

// ---------------------------------------------------------------------------
// K5: per-dst-node softmax aggregation (no max-shift; clamp 60), 4-edge
// unrolled inner loop with interleaved shuffle chains, + head-mean + relu
// + classifier. Head-major lane = (h=lane>>4, c4=(lane&15)*4).
// ---------------------------------------------------------------------------
__device__ __forceinline__ float edge_g(ushort4 r, float xr0, float xr1,
                                        float xr2, float xr3, float4 av,
                                        float& x0, float& x1, float& x2, float& x3) {
  x0 = bf2f(r.x); x1 = bf2f(r.y); x2 = bf2f(r.z); x3 = bf2f(r.w);
  float t0 = x0 + xr0, t1 = x1 + xr1, t2 = x2 + xr2, t3 = x3 + xr3;
  t0 = fmaxf(t0, 0.2f * t0); t1 = fmaxf(t1, 0.2f * t1);
  t2 = fmaxf(t2, 0.2f * t2); t3 = fmaxf(t3, 0.2f * t3);
  return av.x * t0 + av.y * t1 + av.z * t2 + av.w * t3;
}

template <int INLINE_XR>
__global__ __launch_bounds__(256) void k_agg(
    const u16* __restrict__ xls, const u16* __restrict__ xrs,
    const float* __restrict__ ha, const float* __restrict__ Wr,
    const float* __restrict__ br,
    const int* __restrict__ esrc, const int* __restrict__ beg,
    const int* __restrict__ end,
    const float* __restrict__ att, const float* __restrict__ gbias,
    const float* __restrict__ wcls, const float* __restrict__ bcls,
    float* __restrict__ out)
{
  __shared__ u16 wr[INLINE_XR ? GAT_IN * 256 : 64];
  if (INLINE_XR) {
    for (int m = threadIdx.x; m < GAT_IN * 256; m += 256) wr[m] = f2bf(Wr[m]);
    __syncthreads();
  }
  const int lane = threadIdx.x & 63;
  const int n = blockIdx.x * 4 + (threadIdx.x >> 6);
  if (n >= N_NODES) return;

  const float4 av = *(const float4*)(att + lane * 4);

  float xr0, xr1, xr2, xr3;
  if (INLINE_XR) {
    float4 bv = *(const float4*)(br + lane * 4);
    xr0 = bv.x; xr1 = bv.y; xr2 = bv.z; xr3 = bv.w;
    const float* hrow = ha + (size_t)n * 68;
    for (int i = 0; i < GAT_IN; ++i) {
      ushort4 wv = *(const ushort4*)&wr[i * 256 + lane * 4];
      float hv = hrow[i];
      xr0 += hv * bf2f(wv.x); xr1 += hv * bf2f(wv.y);
      xr2 += hv * bf2f(wv.z); xr3 += hv * bf2f(wv.w);
    }
  } else {
    ushort4 qv = *(const ushort4*)(xrs + (size_t)n * 256 + lane * 4);
    xr0 = bf2f(qv.x); xr1 = bf2f(qv.y); xr2 = bf2f(qv.z); xr3 = bf2f(qv.w);
  }

  int kb = beg[n], ke = end[n];
  if (kb < 0) kb = 0;
  if (ke > N_EDGES) ke = N_EDGES;
  int dg = ke - kb; if (dg < 0) dg = 0;

  float l_, c0, c1, c2, c3;
  {  // self-loop
    ushort4 r = *(const ushort4*)(xls + (size_t)n * 256 + lane * 4);
    float x0, x1, x2, x3;
    float g = edge_g(r, xr0, xr1, xr2, xr3, av, x0, x1, x2, x3);
    g += __shfl_xor(g, 1); g += __shfl_xor(g, 2);
    g += __shfl_xor(g, 4); g += __shfl_xor(g, 8);
    float a = __expf(fminf(g, 60.f));
    l_ = a; c0 = a * x0; c1 = a * x1; c2 = a * x2; c3 = a * x3;
  }

  for (int e = 0; e < dg; e += 4) {
    const int rem = dg - e;
    const int i0 = kb + e;
    int s0 = esrc[i0];
    int s1 = (rem > 1) ? esrc[i0 + 1] : s0;
    int s2 = (rem > 2) ? esrc[i0 + 2] : s0;
    int s3 = (rem > 3) ? esrc[i0 + 3] : s0;
    ushort4 r0 = *(const ushort4*)(xls + (size_t)s0 * 256 + lane * 4);
    ushort4 r1 = *(const ushort4*)(xls + (size_t)s1 * 256 + lane * 4);
    ushort4 r2 = *(const ushort4*)(xls + (size_t)s2 * 256 + lane * 4);
    ushort4 r3 = *(const ushort4*)(xls + (size_t)s3 * 256 + lane * 4);
    float xa0, xa1, xa2, xa3, xb0, xb1, xb2, xb3;
    float xc0, xc1, xc2, xc3, xd0, xd1, xd2, xd3;
    float g0 = edge_g(r0, xr0, xr1, xr2, xr3, av, xa0, xa1, xa2, xa3);
    float g1 = edge_g(r1, xr0, xr1, xr2, xr3, av, xb0, xb1, xb2, xb3);
    float g2 = edge_g(r2, xr0, xr1, xr2, xr3, av, xc0, xc1, xc2, xc3);
    float g3 = edge_g(r3, xr0, xr1, xr2, xr3, av, xd0, xd1, xd2, xd3);
    g0 += __shfl_xor(g0, 1); g1 += __shfl_xor(g1, 1);
    g2 += __shfl_xor(g2, 1); g3 += __shfl_xor(g3, 1);
    g0 += __shfl_xor(g0, 2); g1 += __shfl_xor(g1, 2);
    g2 += __shfl_xor(g2, 2); g3 += __shfl_xor(g3, 2);
    g0 += __shfl_xor(g0, 4); g1 += __shfl_xor(g1, 4);
    g2 += __shfl_xor(g2, 4); g3 += __shfl_xor(g3, 4);
    g0 += __shfl_xor(g0, 8); g1 += __shfl_xor(g1, 8);
    g2 += __shfl_xor(g2, 8); g3 += __shfl_xor(g3, 8);
    float a0 = __expf(fminf(g0, 60.f));
    float a1 = (rem > 1) ? __expf(fminf(g1, 60.f)) : 0.f;
    float a2 = (rem > 2) ? __expf(fminf(g2, 60.f)) : 0.f;
    float a3 = (rem > 3) ? __expf(fminf(g3, 60.f)) : 0.f;
    l_ += (a0 + a1) + (a2 + a3);
    c0 += a0 * xa0 + a1 * xb0 + a2 * xc0 + a3 * xd0;
    c1 += a0 * xa1 + a1 * xb1 + a2 * xc1 + a3 * xd1;
    c2 += a0 * xa2 + a1 * xb2 + a2 * xc2 + a3 * xd2;
    c3 += a0 * xa3 + a1 * xb3 + a2 * xc3 + a3 * xd3;
  }

  float inv = 1.f / (l_ + 1e-16f);
  float v0 = c0 * inv, v1 = c1 * inv, v2 = c2 * inv, v3 = c3 * inv;
  v0 += __shfl_xor(v0, 16); v0 += __shfl_xor(v0, 32);
  v1 += __shfl_xor(v1, 16); v1 += __shfl_xor(v1, 32);
  v2 += __shfl_xor(v2, 16); v2 += __shfl_xor(v2, 32);
  v3 += __shfl_xor(v3, 16); v3 += __shfl_xor(v3, 32);
  const int g4 = (lane & 15) * 4;
  const int h = lane >> 4;
  float4 gb = *(const float4*)(gbias + g4);
  v0 = fmaxf(0.25f * v0 + gb.x, 0.f);
  v1 = fmaxf(0.25f * v1 + gb.y, 0.f);
  v2 = fmaxf(0.25f * v2 + gb.z, 0.f);
  v3 = fmaxf(0.25f * v3 + gb.w, 0.f);
  float4 w0 = *(const float4*)(wcls + (g4 + 0) * 16 + h * 4);
  float4 w1 = *(const float4*)(wcls + (g4 + 1) * 16 + h * 4);
  float4 w2 = *(const float4*)(wcls + (g4 + 2) * 16 + h * 4);
  float4 w3 = *(const float4*)(wcls + (g4 + 3) * 16 + h * 4);
  float o0 = v0 * w0.x + v1 * w1.x + v2 * w2.x + v3 * w3.x;
  float o1 = v0 * w0.y + v1 * w1.y + v2 * w2.y + v3 * w3.y;
  float o2 = v0 * w0.z + v1 * w1.z + v2 * w2.z + v3 * w3.z;
  float o3 = v0 * w0.w + v1 * w1.w + v2 * w2.w + v3 * w3.w;
  #pragma unroll
  for (int mm = 1; mm < 16; mm <<= 1) {
    o0 += __shfl_xor(o0, mm); o1 += __shfl_xor(o1, mm);
    o2 += __shfl_xor(o2, mm); o3 += __shfl_xor(o3, mm);
  }
  if ((lane & 15) == 0) {
    float4 bcv = *(const float4*)(bcls + h * 4);
    float4 ov;
    ov.x = o0 + bcv.x; ov.y = o1 + bcv.y; ov.z = o2 + bcv.z; ov.w = o3 + bcv.w;
    *(float4*)(out + (size_t)n * 16 + h * 4) = ov;
  }
}

// ---------------------------------------------------------------------------
extern "C" void kernel_launch(void* const* d_in, const int* in_sizes, int n_in,
                              void* d_out, int out_size, void* d_ws, size_t ws_size,
                              hipStream_t stream)
{
  const float* x     = (const float*)d_in[0];
  const void*  ei    = d_in[1];
  const float* Win   = (const float*)d_in[2];
  const float* bin   = (const float*)d_in[3];
  const float* proto = (const float*)d_in[4];
  const float* Wl    = (const float*)d_in[5];
  const float* bl    = (const float*)d_in[6];
  const float* Wr    = (const float*)d_in[7];
  const float* br    = (const float*)d_in[8];
  const float* att   = (const float*)d_in[9];
  const float* gbias = (const float*)d_in[10];
  const float* wcls  = (const float*)d_in[11];
  const float* bcls  = (const float*)d_in[12];
  float* out = (float*)d_out;

  char* p = (char*)d_ws;
  size_t used = 0;
  auto carve = [&](size_t bytes) {
    char* q = p + used;
    used += (bytes + 255) & ~(size_t)255;
    return (void*)q;
  };
  int* gcount = (int*)carve(256);
  int* deg  = (int*)carve(N_NODES * 4);
  int* beg  = (int*)carve(N_NODES * 4);
  int* end  = (int*)carve(N_NODES * 4);
  int* cur  = (int*)carve(N_NODES * 4);
  int* esrc = (int*)carve(N_EDGES * 4);
  float* ha = (float*)carve((size_t)N_NODES * 68 * 4 + 512);
  u16* xls  = (u16*)carve((size_t)N_NODES * 256 * 2);
  size_t used_min = used + ((size_t)N_NODES * 256 * 2);
  u16* xrs  = (u16*)carve((size_t)N_NODES * 256 * 2);
  const bool full = ws_size >= used_min;

  k_haug<<<391, 512, 0, stream>>>(x, Win, bin, proto, ha, deg, gcount);
  k_hist<<<3125, 256, 0, stream>>>(ei, deg);
  k_lin<<<391, 512, 0, stream>>>(ha, Wl, bl, xls);
  if (full) k_lin<<<391, 512, 0, stream>>>(ha, Wr, br, xrs);
  k_scan1<<<NB_SCAN, 256, 0, stream>>>(deg, gcount, beg, end, cur);
  k_scatter<<<3125, 256, 0, stream>>>(ei, cur, esrc);
  if (full)
    k_agg<0><<<12500, 256, 0, stream>>>(xls, xrs, ha, Wr, br, esrc, beg, end,
                                        att, gbias, wcls, bcls, out);
  else
    k_agg<1><<<12500, 256, 0, stream>>>(xls, xrs, ha, Wr, br, esrc, beg, end,
                                        att, gbias, wcls, bcls, out);
}